// Round 7
// baseline (2181.145 us; speedup 1.0000x reference)
//
#include <hip/hip_runtime.h>
#include <hip/hip_bf16.h>

#define TOK 16384
#define TAU2 0.02f
#define CFENCE asm volatile("" ::: "memory")

typedef __attribute__((ext_vector_type(8))) short short8;
typedef __attribute__((ext_vector_type(4))) float f32x4;

__device__ __forceinline__ unsigned short f32_bf16(float f) {
  __hip_bfloat16 h = __float2bfloat16(f);
  unsigned short u;
  __builtin_memcpy(&u, &h, sizeof(u));
  return u;
}
__device__ __forceinline__ float bf16_f32(unsigned short u) {
  union { unsigned int i; float f; } c; c.i = ((unsigned int)u) << 16; return c.f;
}

// async global->LDS, 16B per lane; LDS dest linear in lane order.
__device__ __forceinline__ void gll16(const unsigned short* g, unsigned short* l) {
  __builtin_amdgcn_global_load_lds(
      (const __attribute__((address_space(1))) unsigned int*)g,
      (__attribute__((address_space(3))) unsigned int*)l, 16, 0, 0);
}

__global__ void zero3(int* a, int* c) {
  if (threadIdx.x == 0) { *a = 0; c[0] = 0; c[1] = 0; }
}

__global__ void cvt_kernel(const float* __restrict__ s, unsigned short* __restrict__ d, int n4) {
  int i = blockIdx.x * 256 + threadIdx.x;
  if (i < n4) {
    float4 v = ((const float4*)s)[i];
    union { unsigned short u[4]; uint2 q; } pk;
    pk.u[0] = f32_bf16(v.x); pk.u[1] = f32_bf16(v.y);
    pk.u[2] = f32_bf16(v.z); pk.u[3] = f32_bf16(v.w);
    ((uint2*)d)[i] = pk.q;
  }
}

// token compaction by selected branch (runs after sel is final)
__global__ void compact_sel(const int* __restrict__ sel, int* __restrict__ idx1,
                            int* __restrict__ idx2, int* __restrict__ cnt) {
  int t = blockIdx.x * 256 + threadIdx.x;
  int s = sel[t];
  if (s == 1) idx1[atomicAdd(&cnt[0], 1)] = t;
  else if (s == 2) idx2[atomicAdd(&cnt[1], 1)] = t;
}

// pad index lists to a multiple of 128 with -1 sentinels; publish padded counts
__global__ void pad_idx(int* __restrict__ idx1, int* __restrict__ idx2,
                        const int* __restrict__ cnt, int* __restrict__ mc) {
  const int tid = threadIdx.x;
  const int n1 = cnt[0], n2 = cnt[1];
  const int p1 = (n1 + 127) & ~(int)127, p2 = (n2 + 127) & ~(int)127;
  if (tid < p1 - n1) idx1[n1 + tid] = -1;
  if (tid < p2 - n2) idx2[n2 + tid] = -1;
  if (tid == 0) { mc[0] = p1; mc[1] = p2; }
}

// XCD-aware decode: 1-D grid of (128 panels) x (2^LOG2NC cols). All col-tiles
// of one row-panel land on the SAME XCD (panel % 8 == xcd) -> shared A panel
// fetched once into that XCD's L2. Bijective for 128 panels.
#define XCD_DECODE(LOG2NC)                                                    \
  const int wgid = blockIdx.x;                                                \
  const int xcd = wgid & 7;                                                   \
  const int slot = wgid >> 3;                                                 \
  const int n0 = (slot & ((1 << (LOG2NC)) - 1)) * 128;                        \
  const int m0 = ((slot >> (LOG2NC)) * 8 + xcd) * 128;

// ---------------------------------------------------------------------------
// bf16 GEMM body: 128x128 tile, BK=32, triple-buffered LDS (48 KB, 3 blk/CU),
// prefetch depth 2 with counted vmcnt (never 0 in steady state), raw
// s_barrier + counted-wait-before-barrier. global_load_lds staging (16B/lane,
// linear LDS dest), 4-chunk XOR swizzle. XCD-aware block decode.
// C[M,N] = A[M,K] * Bw[N,K]^T (+bias), row strides LDA/LDB (elements).
// EPI: 0 = bias -> bf16 store
//      4 = bias -> fp32 scatter store to out row idx[row] (skip idx<0)
//      5 = plain fp32 store, NO bias (bias ptr unused)
// AG:  1 = gather A rows through idx (sentinel -1 clamps to row 0)
// mcp: active row count (padded to 128); blocks past it exit.
// ---------------------------------------------------------------------------
template<int EPI, int AG, int LOG2NC>
__device__ __forceinline__
void gemm_body(const unsigned short* __restrict__ A,
               const unsigned short* __restrict__ Bw,
               const float* __restrict__ bias,
               void* __restrict__ Outv,
               const int* __restrict__ idx, const int* __restrict__ mcp,
               int N, int K, int LDA, int LDB) {
  __shared__ __align__(16) unsigned short As[3 * 128 * 32];
  __shared__ __align__(16) unsigned short Bs[3 * 128 * 32];
  const int tid = threadIdx.x;
  XCD_DECODE(LOG2NC)
  if (mcp && m0 >= *mcp) return;
  const int lane = tid & 63, wave = tid >> 6;
  const int wm = wave >> 1, wn = wave & 1;
  const int quad = lane >> 4, lr = lane & 15;

  // staging: round r in {0,1}; thread t covers row r*64 + (t>>2), chunk t&3
  // (16B chunks of a 64B row). LDS dest linear = t*16B; content = global
  // chunk (t&3) ^ (row&3).
  const int srow = tid >> 2;                   // 0..63
  const int schunk = (tid & 3) ^ (srow & 3);   // pre-swizzled source chunk
  unsigned int aoff[2], boff[2];
  #pragma unroll
  for (int r = 0; r < 2; r++) {
    int row = r * 64 + srow;
    int gr = m0 + row;
    if (AG) { int t = idx[gr]; gr = (t < 0) ? 0 : t; }
    aoff[r] = (unsigned int)gr * (unsigned int)LDA + (unsigned int)(schunk * 8);
    boff[r] = (unsigned int)(n0 + row) * (unsigned int)LDB + (unsigned int)(schunk * 8);
  }
  const int lds_dst = tid * 8;  // shorts; round r adds 2048

  f32x4 acc[4][4] = {};
  const int nk = K >> 5;  // >= 16 for all our shapes

  #define STAGE(T, O)                                                        \
    {                                                                        \
      const unsigned int k0 = (unsigned int)(T) << 5;                        \
      gll16(A + aoff[0] + k0, &As[(O) + lds_dst]);                           \
      gll16(A + aoff[1] + k0, &As[(O) + 2048 + lds_dst]);                    \
      gll16(Bw + boff[0] + k0, &Bs[(O) + lds_dst]);                          \
      gll16(Bw + boff[1] + k0, &Bs[(O) + 2048 + lds_dst]);                   \
    }
  #define COMPUTE(O)                                                         \
    {                                                                        \
      short8 af[4], bfr[4];                                                  \
      _Pragma("unroll")                                                      \
      for (int i = 0; i < 4; i++) {                                          \
        const int row = wm * 64 + i * 16 + lr;                               \
        af[i] = *(const short8*)(&As[(O) + row * 32 + ((quad ^ (row & 3)) << 3)]); \
      }                                                                      \
      _Pragma("unroll")                                                      \
      for (int j = 0; j < 4; j++) {                                          \
        const int row = wn * 64 + j * 16 + lr;                               \
        bfr[j] = *(const short8*)(&Bs[(O) + row * 32 + ((quad ^ (row & 3)) << 3)]); \
      }                                                                      \
      _Pragma("unroll")                                                      \
      for (int i = 0; i < 4; i++)                                            \
        _Pragma("unroll")                                                    \
        for (int j = 0; j < 4; j++)                                          \
          acc[i][j] = __builtin_amdgcn_mfma_f32_16x16x32_bf16(af[i], bfr[j], acc[i][j], 0, 0, 0); \
    }

  int oA = 0, oB = 4096, oC = 8192;
  STAGE(0, oA);
  STAGE(1, oB);

  for (int t = 0; t < nk - 2; t++) {
    STAGE(t + 2, oC);
    asm volatile("s_waitcnt vmcnt(8)" ::: "memory");  // tile t's 4 loads done
    CFENCE; __builtin_amdgcn_s_barrier(); CFENCE;
    COMPUTE(oA);
    CFENCE; __builtin_amdgcn_s_barrier(); CFENCE;
    int tmp = oA; oA = oB; oB = oC; oC = tmp;
  }
  asm volatile("s_waitcnt vmcnt(4)" ::: "memory");
  CFENCE; __builtin_amdgcn_s_barrier(); CFENCE;
  COMPUTE(oA);
  CFENCE; __builtin_amdgcn_s_barrier(); CFENCE;
  { int tmp = oA; oA = oB; oB = oC; oC = tmp; }
  asm volatile("s_waitcnt vmcnt(0)" ::: "memory");
  CFENCE; __builtin_amdgcn_s_barrier(); CFENCE;
  COMPUTE(oA);
  #undef STAGE
  #undef COMPUTE

  // epilogue: C/D layout col=lane&15 (n), row=quad*4+reg (m)
  #pragma unroll
  for (int i = 0; i < 4; i++) {
    const int rbase = m0 + wm * 64 + i * 16 + quad * 4;
    #pragma unroll
    for (int j = 0; j < 4; j++) {
      const int col = n0 + wn * 64 + j * 16 + lr;
      const float bv = (EPI == 5) ? 0.0f : bias[col];
      #pragma unroll
      for (int r = 0; r < 4; r++) {
        const int row = rbase + r;
        float v = acc[i][j][r] + bv;
        if (EPI == 0) {
          ((unsigned short*)Outv)[(size_t)row * N + col] = f32_bf16(v);
        } else if (EPI == 4) {
          const int tk = idx[row];
          if (tk >= 0) ((float*)Outv)[(size_t)tk * N + col] = v;
        } else {  // EPI == 5
          ((float*)Outv)[(size_t)row * N + col] = v;
        }
      }
    }
  }
}

// named shells so rocprof shows per-stage durations
#define GEMM_SHELL(NAME, EPI, AG, LOG2NC)                                      \
__global__ __launch_bounds__(256, 3) void NAME(                                \
    const unsigned short* __restrict__ A,                                      \
    const unsigned short* __restrict__ Bw,                                     \
    const float* __restrict__ bias, void* __restrict__ Outv,                   \
    const int* __restrict__ idx, const int* __restrict__ mcp,                  \
    int N, int K, int LDA, int LDB) {                                          \
  gemm_body<EPI, AG, LOG2NC>(A, Bw, bias, Outv, idx, mcp, N, K, LDA, LDB);     \
}
GEMM_SHELL(g_comp1, 0, 1, 3)   // N=1024 -> 8 cols
GEMM_SHELL(g_comp2, 0, 1, 2)   // N=512  -> 4 cols
GEMM_SHELL(g_adapt1, 0, 0, 3)  // N=1024
GEMM_SHELL(g_adapt2, 0, 0, 2)  // N=512
GEMM_SHELL(g_dec1, 4, 0, 4)    // N=2048 -> 16 cols
GEMM_SHELL(g_dec2, 4, 0, 4)    // N=2048
GEMM_SHELL(g_sel1a, 5, 0, 2)   // G1 = hb[:, :1024] @ W1[:, :1024]^T
GEMM_SHELL(g_sel1b, 5, 0, 2)   // G2 = hb[:, 1024:] @ W1[:, 1024:]^T

// ---------------------------------------------------------------------------
// selector logits from the two half-K GEMM outputs:
//   hid = relu(freq*G1 + imp*G2 + b1); logits = hid @ W2^T + b2.
// argmax + tight-margin flagging (TAU2 covers bf16 GEMM error, ~10x slack).
// One wave per token.
// ---------------------------------------------------------------------------
__global__ __launch_bounds__(256)
void selector_logits2(const float* __restrict__ G1, const float* __restrict__ G2,
                      const float* __restrict__ freq, const float* __restrict__ imp,
                      const float* __restrict__ b1,
                      const float* __restrict__ W2, const float* __restrict__ b2,
                      int* __restrict__ sel, int* __restrict__ risky,
                      int* __restrict__ riskyCount) {
  const int wave = threadIdx.x >> 6, lane = threadIdx.x & 63;
  const int token = blockIdx.x * 4 + wave;
  const float fq = freq[token], im = imp[token];
  const float* g1 = G1 + (size_t)token * 512 + lane * 8;
  const float* g2 = G2 + (size_t)token * 512 + lane * 8;
  const float* bb = b1 + lane * 8;
  float4 a0 = *(const float4*)g1, a1 = *(const float4*)(g1 + 4);
  float4 c0 = *(const float4*)g2, c1 = *(const float4*)(g2 + 4);
  float4 bl0 = *(const float4*)bb, bl1 = *(const float4*)(bb + 4);
  float hid[8];
  hid[0] = fmaxf(fq * a0.x + im * c0.x + bl0.x, 0.f);
  hid[1] = fmaxf(fq * a0.y + im * c0.y + bl0.y, 0.f);
  hid[2] = fmaxf(fq * a0.z + im * c0.z + bl0.z, 0.f);
  hid[3] = fmaxf(fq * a0.w + im * c0.w + bl0.w, 0.f);
  hid[4] = fmaxf(fq * a1.x + im * c1.x + bl1.x, 0.f);
  hid[5] = fmaxf(fq * a1.y + im * c1.y + bl1.y, 0.f);
  hid[6] = fmaxf(fq * a1.z + im * c1.z + bl1.z, 0.f);
  hid[7] = fmaxf(fq * a1.w + im * c1.w + bl1.w, 0.f);
  float p[3];
  #pragma unroll
  for (int c = 0; c < 3; c++) {
    const float* w = W2 + c * 512 + lane * 8;
    float4 w0 = *(const float4*)w, w1 = *(const float4*)(w + 4);
    p[c] = hid[0]*w0.x + hid[1]*w0.y + hid[2]*w0.z + hid[3]*w0.w
         + hid[4]*w1.x + hid[5]*w1.y + hid[6]*w1.z + hid[7]*w1.w;
  }
  #pragma unroll
  for (int off = 32; off >= 1; off >>= 1) {
    #pragma unroll
    for (int c = 0; c < 3; c++) p[c] += __shfl_xor(p[c], off, 64);
  }
  if (lane == 0) {
    float l0 = p[0] + b2[0], l1 = p[1] + b2[1], l2 = p[2] + b2[2];
    int arg = 0; float best = l0;
    if (l1 > best) { best = l1; arg = 1; }
    if (l2 > best) { best = l2; arg = 2; }
    float second;
    if (arg == 0) second = fmaxf(l1, l2);
    else if (arg == 1) second = fmaxf(l0, l2);
    else second = fmaxf(l0, l1);
    sel[token] = arg;
    if (best - second < TAU2) {
      int idx = atomicAdd(riskyCount, 1);
      risky[idx] = token;
    }
  }
}

// exact fp32 selector recompute for near-tie tokens.
__global__ __launch_bounds__(256)
void recheck_exact(const float* __restrict__ h, const float* __restrict__ freq,
                   const float* __restrict__ imp,
                   const float* __restrict__ W1, const float* __restrict__ b1,
                   const float* __restrict__ W2, const float* __restrict__ b2,
                   const int* __restrict__ risky, const int* __restrict__ riskyCount,
                   int* __restrict__ sel) {
  __shared__ float h_sh[2048];
  __shared__ float hid_sh[512];
  const int n = *riskyCount;
  const int tid = threadIdx.x;
  for (int ri = blockIdx.x; ri < n; ri += gridDim.x) {
    const int token = risky[ri];
    {
      const float s = (tid < 128) ? freq[token] : imp[token];
      const float4* src = (const float4*)(h + (size_t)token * 2048) + tid * 2;
      float4 v0 = src[0], v1 = src[1];
      v0.x *= s; v0.y *= s; v0.z *= s; v0.w *= s;
      v1.x *= s; v1.y *= s; v1.z *= s; v1.w *= s;
      ((float4*)h_sh)[tid * 2] = v0;
      ((float4*)h_sh)[tid * 2 + 1] = v1;
    }
    __syncthreads();
    #pragma unroll
    for (int half = 0; half < 2; half++) {
      const int o = tid + half * 256;
      const float* wrow = W1 + (size_t)o * 2048;
      float a0 = 0.f, a1 = 0.f, a2 = 0.f, a3 = 0.f;
      for (int k = 0; k < 2048; k += 16) {
        float4 w0 = *(const float4*)(wrow + k);
        float4 w1v = *(const float4*)(wrow + k + 4);
        float4 w2v = *(const float4*)(wrow + k + 8);
        float4 w3v = *(const float4*)(wrow + k + 12);
        float4 x0 = *(const float4*)(h_sh + k);
        float4 x1 = *(const float4*)(h_sh + k + 4);
        float4 x2 = *(const float4*)(h_sh + k + 8);
        float4 x3 = *(const float4*)(h_sh + k + 12);
        a0 += w0.x*x0.x + w0.y*x0.y + w0.z*x0.z + w0.w*x0.w;
        a1 += w1v.x*x1.x + w1v.y*x1.y + w1v.z*x1.z + w1v.w*x1.w;
        a2 += w2v.x*x2.x + w2v.y*x2.y + w2v.z*x2.z + w2v.w*x2.w;
        a3 += w3v.x*x3.x + w3v.y*x3.y + w3v.z*x3.z + w3v.w*x3.w;
      }
      hid_sh[o] = fmaxf((a0 + a1) + (a2 + a3) + b1[o], 0.0f);
    }
    __syncthreads();
    if (tid < 64) {
      const int lane = tid;
      const float* hs = &hid_sh[lane * 8];
      float l[3];
      #pragma unroll
      for (int c = 0; c < 3; c++) {
        const float* w = W2 + c * 512 + lane * 8;
        float s = 0.0f;
        #pragma unroll
        for (int e = 0; e < 8; e++) s += hs[e] * w[e];
        l[c] = s;
      }
      #pragma unroll
      for (int off = 32; off >= 1; off >>= 1)
        #pragma unroll
        for (int c = 0; c < 3; c++) l[c] += __shfl_xor(l[c], off, 64);
      if (lane == 0) {
        float l0 = l[0] + b2[0], l1 = l[1] + b2[1], l2 = l[2] + b2[2];
        int arg = 0; float best = l0;
        if (l1 > best) { best = l1; arg = 1; }
        if (l2 > best) { arg = 2; }
        sel[token] = arg;
      }
    }
    __syncthreads();
  }
}

__global__ __launch_bounds__(256)
void copy_sel0(const float* __restrict__ h, const int* __restrict__ sel,
               float* __restrict__ out) {
  for (int token = blockIdx.x; token < TOK; token += gridDim.x) {
    if (sel[token] != 0) continue;
    const float4* src = (const float4*)(h + (size_t)token * 2048);
    float4* dst = (float4*)(out + (size_t)token * 2048);
    dst[threadIdx.x] = src[threadIdx.x];
    dst[threadIdx.x + 256] = src[threadIdx.x + 256];
  }
}

extern "C" void kernel_launch(void* const* d_in, const int* in_sizes, int n_in,
                              void* d_out, int out_size, void* d_ws, size_t ws_size,
                              hipStream_t stream) {
  const float* h        = (const float*)d_in[0];
  const float* freq     = (const float*)d_in[1];
  const float* imp      = (const float*)d_in[2];
  const float* comp1W   = (const float*)d_in[3];
  const float* comp1b   = (const float*)d_in[4];
  const float* adapt1W  = (const float*)d_in[5];
  const float* adapt1b  = (const float*)d_in[6];
  const float* decomp1W = (const float*)d_in[7];
  const float* decomp1b = (const float*)d_in[8];
  const float* comp2W   = (const float*)d_in[9];
  const float* comp2b   = (const float*)d_in[10];
  const float* adapt2W  = (const float*)d_in[11];
  const float* adapt2b  = (const float*)d_in[12];
  const float* decomp2W = (const float*)d_in[13];
  const float* decomp2b = (const float*)d_in[14];
  const float* sel1W    = (const float*)d_in[15];
  const float* sel1b    = (const float*)d_in[16];
  const float* sel2W    = (const float*)d_in[17];
  const float* sel2b    = (const float*)d_in[18];
  float* out = (float*)d_out;

  char* ws = (char*)d_ws;
  size_t off = 0;
  auto alloc = [&](size_t bytes) -> void* {
    void* p = ws + off; off += (bytes + 255) & ~(size_t)255; return p;
  };
  unsigned short* wb_comp1   = (unsigned short*)alloc((size_t)1024 * 2048 * 2);
  unsigned short* wb_adapt1  = (unsigned short*)alloc((size_t)1024 * 1024 * 2);
  unsigned short* wb_decomp1 = (unsigned short*)alloc((size_t)2048 * 1024 * 2);
  unsigned short* wb_comp2   = (unsigned short*)alloc((size_t)512 * 2048 * 2);
  unsigned short* wb_adapt2  = (unsigned short*)alloc((size_t)512 * 512 * 2);
  unsigned short* wb_decomp2 = (unsigned short*)alloc((size_t)2048 * 512 * 2);
  unsigned short* wb_sel1    = (unsigned short*)alloc((size_t)512 * 2048 * 2);
  float*          hidf       = (float*)alloc((size_t)TOK * 512 * 4);   // G1
  unsigned short* c1         = (unsigned short*)alloc((size_t)TOK * 1024 * 2);
  unsigned short* a1         = (unsigned short*)alloc((size_t)TOK * 1024 * 2);
  int* sel        = (int*)alloc((size_t)TOK * 4);
  int* risky      = (int*)alloc((size_t)TOK * 4);
  int* riskyCount = (int*)alloc(256);
  int* idx1       = (int*)alloc((size_t)TOK * 4);
  int* idx2       = (int*)alloc((size_t)TOK * 4);
  int* cnt        = (int*)alloc(256);   // [0]=n1, [1]=n2
  int* mc         = (int*)alloc(256);   // [0]=p1, [1]=p2 (padded to 128)
  // total ws: ~107 MB (below proven 115 MB footprint)

  // hb (bf16 h, 64 MB) lives in out[0..64MB); G2 (32 MB) in out[64..96MB).
  // Both dead before any out writes (decomp/copy stages run last).
  unsigned short* hb = (unsigned short*)out;
  float* G2 = out + (size_t)16 * 1024 * 1024;   // float offset = 64 MB
  // branch-2 intermediates alias hidf/G1 (dead after selector_logits2)
  unsigned short* c2 = (unsigned short*)hidf;                       // 16 MB
  unsigned short* a2 = (unsigned short*)hidf + (size_t)TOK * 512;   // 16 MB

  zero3<<<1, 64, 0, stream>>>(riskyCount, cnt);

  auto cvt = [&](const float* s, unsigned short* d, int n) {
    cvt_kernel<<<(n / 4 + 255) / 256, 256, 0, stream>>>(s, d, n / 4);
  };
  cvt(comp1W,   wb_comp1,   1024 * 2048);
  cvt(adapt1W,  wb_adapt1,  1024 * 1024);
  cvt(decomp1W, wb_decomp1, 2048 * 1024);
  cvt(comp2W,   wb_comp2,   512 * 2048);
  cvt(adapt2W,  wb_adapt2,  512 * 512);
  cvt(decomp2W, wb_decomp2, 2048 * 512);
  cvt(sel1W,    wb_sel1,    512 * 2048);
  cvt(h,        hb,         TOK * 2048);   // bf16 copy of h

  // selector half-K GEMMs over plain bf16 hb:
  //   G1 = hb[:, :1024] @ W1[:, :1024]^T ; G2 = hb[:, 1024:] @ W1[:, 1024:]^T
  g_sel1a<<<4 * 128, 256, 0, stream>>>(
      hb, wb_sel1, nullptr, hidf, nullptr, nullptr, 512, 1024, 2048, 2048);
  g_sel1b<<<4 * 128, 256, 0, stream>>>(
      hb + 1024, wb_sel1 + 1024, nullptr, G2, nullptr, nullptr, 512, 1024, 2048, 2048);
  // hid = relu(freq*G1 + imp*G2 + b1); logits; argmax + risky flag
  selector_logits2<<<TOK / 4, 256, 0, stream>>>(
      hidf, G2, freq, imp, sel1b, sel2W, sel2b, sel, risky, riskyCount);
  recheck_exact<<<256, 256, 0, stream>>>(h, freq, imp, sel1W, sel1b, sel2W, sel2b,
                                         risky, riskyCount, sel);

  // token compaction: branch GEMMs only run over their selected tokens
  compact_sel<<<TOK / 256, 256, 0, stream>>>(sel, idx1, idx2, cnt);
  pad_idx<<<1, 256, 0, stream>>>(idx1, idx2, cnt, mc);

  // both comp GEMMs first (they read hb, which lives in out)
  g_comp1<<<8 * 128, 256, 0, stream>>>(
      hb, wb_comp1, comp1b, c1, idx1, mc + 0, 1024, 2048, 2048, 2048);
  g_comp2<<<4 * 128, 256, 0, stream>>>(
      hb, wb_comp2, comp2b, c2, idx2, mc + 1, 512, 2048, 2048, 2048);
  // adaptors
  g_adapt1<<<8 * 128, 256, 0, stream>>>(
      c1, wb_adapt1, adapt1b, a1, nullptr, mc + 0, 1024, 1024, 1024, 1024);
  g_adapt2<<<4 * 128, 256, 0, stream>>>(
      c2, wb_adapt2, adapt2b, a2, nullptr, mc + 1, 512, 512, 512, 512);
  // decompressors scatter into out (hb/G2 now dead)
  g_dec1<<<16 * 128, 256, 0, stream>>>(
      a1, wb_decomp1, decomp1b, out, idx1, mc + 0, 2048, 1024, 1024, 1024);
  g_dec2<<<16 * 128, 256, 0, stream>>>(
      a2, wb_decomp2, decomp2b, out, idx2, mc + 1, 2048, 512, 512, 512);

  // sel==0 tokens: exact fp32 passthrough of h
  copy_sel0<<<2048, 256, 0, stream>>>(h, sel, out);
}